// Round 6
// baseline (353.923 us; speedup 1.0000x reference)
//
#include <hip/hip_runtime.h>
#include <math.h>

constexpr int NFFT = 524288;   // 2^19 >= T + L - 1 = 485099
constexpr int N1   = 512;      // column FFT length (strided dim)
constexpr int N2   = 1024;     // row FFT length (contiguous dim)
constexpr int TT   = 441000;   // multiple of 4
constexpr int IRL  = 44100;    // multiple of 4
constexpr int NSIG = 16;       // 32 real batches packed as 16 complex signals
constexpr int C1   = 16;       // columns per tile in stage1/3
constexpr int TILE = N1 * C1;  // 8192 complex: one (all-k1 x 16-n2) tile

// bufA/irA layout is TILED: addr = (n2/16)*TILE + k1*16 + (n2%16).
// Ht stores H' = dry + wet*H (dry path folded into spectrum; FFT(delta)=1).
// twg: W_1024 twiddle table published by stage1 block 0, loaded by stage2.

// -2*pi/NFFT
constexpr float ANG0   = -1.1984224905891939e-5f;
constexpr float NTWOPI = -6.2831853071795864769f;

__device__ inline float2 cmulf(float2 a, float2 b) {
    return make_float2(a.x * b.x - a.y * b.y, a.x * b.y + a.y * b.x);
}
__device__ inline float2 cadd(float2 a, float2 b) { return make_float2(a.x + b.x, a.y + b.y); }
__device__ inline float2 csub(float2 a, float2 b) { return make_float2(a.x - b.x, a.y - b.y); }

template<bool INV>
__device__ inline void bfly4(const float2* u, float2 w1, float2 w2, float2 w3, float2* o) {
    float2 t0 = cadd(u[0], u[2]);
    float2 t1 = csub(u[0], u[2]);
    float2 t2 = cadd(u[1], u[3]);
    float2 t3 = csub(u[1], u[3]);
    float2 r3 = INV ? make_float2(-t3.y, t3.x) : make_float2(t3.y, -t3.x);
    o[0] = cadd(t0, t2);
    o[1] = cmulf(cadd(t1, r3), w1);
    o[2] = cmulf(csub(t0, t2), w2);
    o[3] = cmulf(csub(t1, r3), w3);
}
template<bool INV>
__device__ inline void bfly4_nw(const float2* u, float2* o) {
    float2 t0 = cadd(u[0], u[2]);
    float2 t1 = csub(u[0], u[2]);
    float2 t2 = cadd(u[1], u[3]);
    float2 t3 = csub(u[1], u[3]);
    float2 r3 = INV ? make_float2(-t3.y, t3.x) : make_float2(t3.y, -t3.x);
    o[0] = cadd(t0, t2);
    o[1] = cadd(t1, r3);
    o[2] = csub(t0, t2);
    o[3] = csub(t1, r3);
}

// Per-thread register twiddles for the 4 radix-4 passes of the 512-FFT.
// pass p uses W_512^{e}, W^{2e}, W^{3e} with e = s*(f>>logs) fixed per thread.
template<bool INV>
__device__ inline void make_w512(float2 (&w)[4][3], int tid) {
    const int f = tid & 127;
    const int ee[4] = { f, 4 * (f >> 2), 16 * (f >> 4), 64 * (f >> 6) };
#pragma unroll
    for (int p = 0; p < 4; ++p)
#pragma unroll
        for (int j = 0; j < 3; ++j) {
            float sn, cs;
            __sincosf(NTWOPI * (float)((j + 1) * ee[p]) * (1.0f / (float)N1), &sn, &cs);
            w[p][j] = make_float2(cs, INV ? -sn : sn);
        }
}

// First 4 radix-4 passes (s=1,4,16,64) of the 512-FFT over 16 XOR-swizzled
// sequences; 1024 threads; twiddles from registers (no LDS table).
template<bool INV>
__device__ inline void fft512_4p_reg(float2* buf, const float2 (&w)[4][3], int tid) {
    const int f  = tid & 127;
    const int cb = tid >> 7;          // 0..7 (wave-uniform)
    int s = 1, logs = 0;
#pragma unroll
    for (int pass = 0; pass < 4; ++pass) {
        const int p = f >> logs;
        const int q = f & (s - 1);
        const int wb = q + 4 * s * p;
        float2 u[2][4];
#pragma unroll
        for (int k = 0; k < 2; ++k) {
            const int c = cb + 8 * k;
            float2* sb = buf + c * N1;
#pragma unroll
            for (int j = 0; j < 4; ++j) u[k][j] = sb[(f + 128 * j) ^ c];
        }
        __syncthreads();
#pragma unroll
        for (int k = 0; k < 2; ++k) {
            const int c = cb + 8 * k;
            float2* sb = buf + c * N1;
            float2 o[4];
            bfly4<INV>(u[k], w[pass][0], w[pass][1], w[pass][2], o);
            sb[wb ^ c]           = o[0];
            sb[(wb + s) ^ c]     = o[1];
            sb[(wb + 2 * s) ^ c] = o[2];
            sb[(wb + 3 * s) ^ c] = o[3];
        }
        __syncthreads();
        s <<= 2; logs += 2;
    }
}

// Radix-4 passes [FIRST, FIRST+COUNT) of the 1024-FFT over one row in LDS.
template<bool INV, int FIRST, int COUNT>
__device__ void fft1024_mid(float2* buf, const float2* __restrict__ tw, int tid) {
    const int f = tid & 255;
    const int r = tid >> 8;
    float2* sb = buf + r * N2;
    int s = 1 << (2 * FIRST), logs = 2 * FIRST;
#pragma unroll
    for (int pass = 0; pass < COUNT; ++pass) {
        const int p = f >> logs;
        const int q = f & (s - 1);
        const int wb = q + 4 * s * p;
        const int e = p * s;
        float2 w1 = tw[e], w2 = tw[2 * e], w3 = tw[3 * e];
        if (INV) { w1.y = -w1.y; w2.y = -w2.y; w3.y = -w3.y; }
        float2 u[4];
#pragma unroll
        for (int j = 0; j < 4; ++j) u[j] = sb[f + 256 * j];
        __syncthreads();
        float2 o[4];
        bfly4<INV>(u, w1, w2, w3, o);
        sb[wb]         = o[0];
        sb[wb + s]     = o[1];
        sb[wb + 2 * s] = o[2];
        sb[wb + 3 * s] = o[3];
        __syncthreads();
        s <<= 2; logs += 2;
    }
}

// ---- stage1: pipelined multi-tile blocks (128 KB LDS double buffer) ----
// tile t = sig*64 + colblk; sig==16 is the IR. 1088 tiles over 256 blocks.

#define S1_LOAD(t_) do {                                                      \
    const int sig_ = (t_) >> 6; const int col0_ = ((t_) & 63) * C1;           \
    const int c4_ = (tid & 3) * 4;                                            \
    if (sig_ < NSIG) {                                                        \
        const float* xa_ = x + (size_t)(2 * sig_) * TT;                       \
        const float* xb_ = xa_ + TT;                                          \
        int n_ = (tid >> 2) * N2 + col0_ + c4_;                               \
        ra0 = make_float4(0.f,0.f,0.f,0.f); rb0 = ra0;                        \
        if (n_ < TT) { ra0 = *(const float4*)(xa_ + n_);                      \
                       rb0 = *(const float4*)(xb_ + n_); }                    \
        n_ = ((tid >> 2) + 256) * N2 + col0_ + c4_;                           \
        ra1 = make_float4(0.f,0.f,0.f,0.f); rb1 = ra1;                        \
        if (n_ < TT) { ra1 = *(const float4*)(xa_ + n_);                      \
                       rb1 = *(const float4*)(xb_ + n_); }                    \
    } else {                                                                  \
        int n_ = (tid >> 2) * N2 + col0_ + c4_;                               \
        ra0 = make_float4(0.f,0.f,0.f,0.f); rb0 = ra0;                        \
        if (n_ < IRL) ra0 = *(const float4*)(ir + n_);                        \
        n_ = ((tid >> 2) + 256) * N2 + col0_ + c4_;                           \
        ra1 = make_float4(0.f,0.f,0.f,0.f); rb1 = ra1;                        \
        if (n_ < IRL) ra1 = *(const float4*)(ir + n_);                        \
    }                                                                         \
} while (0)

#define S1_WRITE(db_) do {                                                    \
    const int c4_ = (tid & 3) * 4;                                            \
    int n1_ = tid >> 2;                                                       \
    (db_)[(c4_+0)*N1 + (n1_^(c4_+0))] = make_float2(ra0.x, rb0.x);            \
    (db_)[(c4_+1)*N1 + (n1_^(c4_+1))] = make_float2(ra0.y, rb0.y);            \
    (db_)[(c4_+2)*N1 + (n1_^(c4_+2))] = make_float2(ra0.z, rb0.z);            \
    (db_)[(c4_+3)*N1 + (n1_^(c4_+3))] = make_float2(ra0.w, rb0.w);            \
    n1_ += 256;                                                               \
    (db_)[(c4_+0)*N1 + (n1_^(c4_+0))] = make_float2(ra1.x, rb1.x);            \
    (db_)[(c4_+1)*N1 + (n1_^(c4_+1))] = make_float2(ra1.y, rb1.y);            \
    (db_)[(c4_+2)*N1 + (n1_^(c4_+2))] = make_float2(ra1.z, rb1.z);            \
    (db_)[(c4_+3)*N1 + (n1_^(c4_+3))] = make_float2(ra1.w, rb1.w);            \
} while (0)

__global__ __launch_bounds__(1024) void k_stage1(const float* __restrict__ x,
                                                 const float* __restrict__ ir,
                                                 float2* __restrict__ bufA,
                                                 float2* __restrict__ irA,
                                                 float2* __restrict__ twg) {
    __shared__ float2 bufs[2][C1 * N1];   // 128 KB -> 1 block/CU, pipelined
    const int tid = threadIdx.x;

    if (blockIdx.x == 0) {                // publish W_1024 table for stage2
        float sn, cs;
        __sincosf(NTWOPI * (float)tid * (1.0f / (float)N2), &sn, &cs);
        twg[tid] = make_float2(cs, sn);
    }

    float2 wreg[4][3];
    make_w512<false>(wreg, tid);

    const int b     = blockIdx.x;
    const int start = (b < 64) ? b * 5 : 64 * 5 + (b - 64) * 4;
    const int cnt   = (b < 64) ? 5 : 4;

    float4 ra0, ra1, rb0, rb1;
    S1_LOAD(start);
    S1_WRITE(bufs[0]);

    int t = start;
    for (int i = 0; i < cnt; ++i) {
        float2* cb_ = bufs[i & 1];
        float2* nb_ = bufs[(i & 1) ^ 1];
        const bool more = (i + 1 < cnt);
        __syncthreads();                  // staging of cb_ visible (drains old stores)
        if (more) S1_LOAD(t + 1);         // in flight across the FFT's lgkm barriers

        fft512_4p_reg<false>(cb_, wreg, tid);

        if (more) S1_WRITE(nb_);          // waits the loads here

        // epilogue: final radix-2 + inter-stage twiddle + tiled store
        {
            const int sig  = t >> 6;
            const int cbk  = t & 63;
            float2* dst  = (sig < NSIG) ? (bufA + (size_t)sig * NFFT) : irA;
            float2* dstt = dst + (size_t)cbk * TILE;
            const int c  = tid & 15;
            const int fr = tid >> 4;          // 0..63
            const int n2 = cbk * C1 + c;
            float2 w0, s64, s256;
            float sn, cs;
            __sincosf(ANG0 * (float)(n2 * fr), &sn, &cs);   w0   = make_float2(cs, sn);
            __sincosf(ANG0 * (float)(n2 * 64), &sn, &cs);   s64  = make_float2(cs, sn);
            __sincosf(ANG0 * (float)(n2 * 256), &sn, &cs);  s256 = make_float2(cs, sn);
#pragma unroll
            for (int it = 0; it < 4; ++it) {
                const int fo = fr + 64 * it;  // 0..255
                float2 a  = cb_[c * N1 + (fo ^ c)];
                float2 b2 = cb_[c * N1 + ((fo + 256) ^ c)];
                float2 X0 = cadd(a, b2);
                float2 X1 = csub(a, b2);
                dstt[fo * C1 + c]         = cmulf(X0, w0);
                dstt[(fo + 256) * C1 + c] = cmulf(X1, cmulf(w0, s256));
                w0 = cmulf(w0, s64);
            }
        }
        ++t;
    }
}

// Stage 2, IR path: forward 1024-FFT -> H, store H' = dry + wet*H. Row-major.
__global__ __launch_bounds__(256) void k_stage2_ir(const float2* __restrict__ src,
                                                   float2* __restrict__ dst,
                                                   const float* __restrict__ wet_param,
                                                   const float2* __restrict__ twg) {
    __shared__ float2 buf[N2];                       // 8 KB
    __shared__ __align__(16) float2 tw[N2];          // 8 KB, loaded from twg
    const int k1  = blockIdx.x;
    const int tid = threadIdx.x;

#pragma unroll
    for (int it = 0; it < 2; ++it)
        ((float4*)tw)[tid + 256 * it] = ((const float4*)twg)[tid + 256 * it];
#pragma unroll
    for (int it = 0; it < 2; ++it) {
        const int qi   = tid + 256 * it;    // 512 float4 = one row
        const int tile = qi >> 3;
        const int q8   = qi & 7;
        ((float4*)buf)[qi] =
            ((const float4*)src)[(size_t)tile * (TILE / 2) + k1 * 8 + q8];
    }
    __syncthreads();

    fft1024_mid<false, 0, 4>(buf, tw, tid);

    const float wet = 1.0f / (1.0f + expf(-wet_param[0]));
    const float dry = 1.0f - wet;

    const int f = tid;
    float2 u[4], o[4];
#pragma unroll
    for (int j = 0; j < 4; ++j) u[j] = buf[f + 256 * j];
    bfly4_nw<false>(u, o);
#pragma unroll
    for (int j = 0; j < 4; ++j)
        dst[(size_t)k1 * N2 + f + 256 * j] =
            make_float2(dry + wet * o[j].x, wet * o[j].y);
}

// Stage 2: fwd 1024-FFT, * H', inv 1024-FFT, conj inter-stage twiddle, store.
// 256-thread blocks, one row each; twiddle table from global. IN-PLACE safe.
__global__ __launch_bounds__(256) void k_stage2(const float2* __restrict__ src,
                                                float2* __restrict__ dst,
                                                const float2* __restrict__ Ht,
                                                const float2* __restrict__ twg) {
    __shared__ float2 buf[N2];                       // 8 KB
    __shared__ __align__(16) float2 tw[N2];          // 8 KB
    const int flat = blockIdx.x;      // = sig*N1 + k1
    const int sg   = flat >> 9;
    const int k1   = flat & (N1 - 1);
    const int tid  = threadIdx.x;     // 0..255

#pragma unroll
    for (int it = 0; it < 2; ++it)
        ((float4*)tw)[tid + 256 * it] = ((const float4*)twg)[tid + 256 * it];
#pragma unroll
    for (int it = 0; it < 2; ++it) {
        const int qi   = tid + 256 * it;
        const int tile = qi >> 3;
        const int q8   = qi & 7;
        ((float4*)buf)[qi] =
            ((const float4*)src)[(size_t)sg * (NFFT / 2) +
                                 (size_t)tile * (TILE / 2) + k1 * 8 + q8];
    }
    // H' prefetch into registers; consumed after the forward FFT.
    const int f = tid;
    float2 h[4];
#pragma unroll
    for (int j = 0; j < 4; ++j) h[j] = Ht[(size_t)k1 * N2 + f + 256 * j];
    __syncthreads();

    fft1024_mid<false, 0, 4>(buf, tw, tid);

    {   // fwd p4 (unit tw) -> * H' -> inv p0 (conj W_1024^{f,2f,3f}), in regs
        float2 u[4];
#pragma unroll
        for (int j = 0; j < 4; ++j) u[j] = buf[f + 256 * j];
        __syncthreads();   // WAR guard
        float2 w1 = tw[f], w2 = tw[2 * f], w3 = tw[3 * f];
        w1.y = -w1.y; w2.y = -w2.y; w3.y = -w3.y;
        float2 o[4], v[4], o2[4];
        bfly4_nw<false>(u, o);
#pragma unroll
        for (int j = 0; j < 4; ++j) v[j] = cmulf(o[j], h[j]);
        bfly4<true>(v, w1, w2, w3, o2);
#pragma unroll
        for (int j = 0; j < 4; ++j) buf[4 * f + j] = o2[j];   // wb=4f, s=1
        __syncthreads();
    }

    fft1024_mid<true, 1, 3>(buf, tw, tid);   // inv passes s=4,16,64

    // inv final pass (s=256, unit tw) + conj twiddle recurrence + store
    float2 u[4], o[4];
#pragma unroll
    for (int j = 0; j < 4; ++j) u[j] = buf[f + 256 * j];
    bfly4_nw<true>(u, o);
    float2 w, st;
    {
        float sn, cs;
        __sincosf(-ANG0 * (float)(f * k1), &sn, &cs);   w  = make_float2(cs, sn);
        __sincosf(-ANG0 * (float)(256 * k1), &sn, &cs); st = make_float2(cs, sn);
    }
    float2* db = dst + (size_t)sg * NFFT;
#pragma unroll
    for (int j = 0; j < 4; ++j) {
        const int n2 = f + 256 * j;
        db[(size_t)(n2 >> 4) * TILE + k1 * C1 + (n2 & 15)] = cmulf(o[j], w);
        w = cmulf(w, st);
    }
}

// ---- stage3: pipelined multi-tile blocks (128 KB LDS double buffer) ----

#define S3_LOAD(t_) do {                                                      \
    const float2* st_ = bufB + (size_t)((t_) >> 6) * NFFT                     \
                             + (size_t)((t_) & 63) * TILE;                    \
    const int cp_ = tid & 7; const int k1b_ = tid >> 3;                       \
    v0 = ((const float4*)st_)[(k1b_      ) * 8 + cp_];                        \
    v1 = ((const float4*)st_)[(k1b_ + 128) * 8 + cp_];                        \
    v2 = ((const float4*)st_)[(k1b_ + 256) * 8 + cp_];                        \
    v3 = ((const float4*)st_)[(k1b_ + 384) * 8 + cp_];                        \
} while (0)

#define S3_WRITE(db_) do {                                                    \
    const int cp_ = tid & 7; const int k1b_ = tid >> 3;                       \
    const int ca_ = 2 * cp_, cb2_ = 2 * cp_ + 1;                              \
    (db_)[ca_*N1  + ((k1b_      ) ^ ca_ )] = make_float2(v0.x, v0.y);         \
    (db_)[cb2_*N1 + ((k1b_      ) ^ cb2_)] = make_float2(v0.z, v0.w);         \
    (db_)[ca_*N1  + ((k1b_ + 128) ^ ca_ )] = make_float2(v1.x, v1.y);         \
    (db_)[cb2_*N1 + ((k1b_ + 128) ^ cb2_)] = make_float2(v1.z, v1.w);         \
    (db_)[ca_*N1  + ((k1b_ + 256) ^ ca_ )] = make_float2(v2.x, v2.y);         \
    (db_)[cb2_*N1 + ((k1b_ + 256) ^ cb2_)] = make_float2(v2.z, v2.w);         \
    (db_)[ca_*N1  + ((k1b_ + 384) ^ ca_ )] = make_float2(v3.x, v3.y);         \
    (db_)[cb2_*N1 + ((k1b_ + 384) ^ cb2_)] = make_float2(v3.z, v3.w);         \
} while (0)

__global__ __launch_bounds__(1024) void k_stage3(const float2* __restrict__ bufB,
                                                 float* __restrict__ out) {
    __shared__ float2 bufs[2][C1 * N1];   // 128 KB
    const int tid = threadIdx.x;

    float2 wreg[4][3];
    make_w512<true>(wreg, tid);

    const float ws = 1.0f / (float)NFFT;

    const int b = blockIdx.x;             // 256 blocks x 4 tiles = 1024 tiles
    int t = b * 4;

    float4 v0, v1, v2, v3;
    S3_LOAD(t);
    S3_WRITE(bufs[0]);

    for (int i = 0; i < 4; ++i) {
        float2* cb_ = bufs[i & 1];
        float2* nb_ = bufs[(i & 1) ^ 1];
        const bool more = (i + 1 < 4);
        __syncthreads();
        if (more) S3_LOAD(t + 1);

        fft512_4p_reg<true>(cb_, wreg, tid);

        if (more) S3_WRITE(nb_);

        // epilogue: final radix-2 + unpack + 1/NFFT scale + stores
        {
            const int sig  = t >> 6;
            const int col0 = (t & 63) * C1;
            float* oa = out + (size_t)(2 * sig) * TT;
            float* ob = oa + TT;
            const int c4 = (tid & 3) * 4;
            const int fo = tid >> 2;          // 0..255
            float2 y0[4], y1[4];
#pragma unroll
            for (int jj = 0; jj < 4; ++jj) {
                const int c = c4 + jj;
                float2 a  = cb_[c * N1 + (fo ^ c)];
                float2 b2 = cb_[c * N1 + ((fo + 256) ^ c)];
                y0[jj] = cadd(a, b2);
                y1[jj] = csub(a, b2);
            }
#pragma unroll
            for (int h = 0; h < 2; ++h) {
                const int row = fo + 256 * h;
                const int n   = row * N2 + col0 + c4;
                if (n < TT) {
                    const float2* yy = h ? y1 : y0;
                    float4 ra, rb2;
                    ra.x = ws * yy[0].x;  ra.y = ws * yy[1].x;
                    ra.z = ws * yy[2].x;  ra.w = ws * yy[3].x;
                    rb2.x = ws * yy[0].y; rb2.y = ws * yy[1].y;
                    rb2.z = ws * yy[2].y; rb2.w = ws * yy[3].y;
                    *(float4*)(oa + n) = ra;
                    *(float4*)(ob + n) = rb2;
                }
            }
        }
        ++t;
    }
}

// Correctness fallback if workspace is too small: direct time-domain conv.
__global__ __launch_bounds__(256) void k_direct(const float* __restrict__ x,
                                                const float* __restrict__ ir,
                                                const float* __restrict__ wet_param,
                                                float* __restrict__ out) {
    __shared__ float irs[1024];
    const int b = blockIdx.y;
    const int n = blockIdx.x * 256 + threadIdx.x;
    float acc = 0.0f;
    for (int k0 = 0; k0 < IRL; k0 += 1024) {
        __syncthreads();
        for (int j = threadIdx.x; j < 1024; j += 256) {
            const int k = k0 + j;
            irs[j] = (k < IRL) ? ir[k] : 0.0f;
        }
        __syncthreads();
        if (n < TT) {
            const int kend = min(1024, n - k0 + 1);
            for (int k = 0; k < kend; ++k)
                acc += irs[k] * x[(size_t)b * TT + (n - k0 - k)];
        }
    }
    if (n < TT) {
        const float wet = 1.0f / (1.0f + expf(-wet_param[0]));
        out[(size_t)b * TT + n] = (1.0f - wet) * x[(size_t)b * TT + n] + wet * acc;
    }
}

extern "C" void kernel_launch(void* const* d_in, const int* in_sizes, int n_in,
                              void* d_out, int out_size, void* d_ws, size_t ws_size,
                              hipStream_t stream) {
    (void)in_sizes; (void)n_in; (void)out_size;
    const float* x   = (const float*)d_in[0];
    const float* ir  = (const float*)d_in[1];
    const float* wet = (const float*)d_in[2];
    float* out = (float*)d_out;

    // ws: Ht(NFFT) + irA(NFFT) + bufA(16*NFFT) + twg(N2); stage2 in-place.
    const size_t need =
        ((size_t)(2 + NSIG) * (size_t)NFFT + (size_t)N2) * sizeof(float2);
    if (ws_size < need) {
        dim3 g((TT + 255) / 256, 32);
        k_direct<<<g, 256, 0, stream>>>(x, ir, wet, out);
        return;
    }

    float2* Ht   = (float2*)d_ws;
    float2* irA  = Ht + NFFT;
    float2* bufA = irA + NFFT;
    float2* twg  = bufA + (size_t)NSIG * NFFT;

    k_stage1<<<dim3(256), 1024, 0, stream>>>(x, ir, bufA, irA, twg);
    k_stage2_ir<<<dim3(N1), 256, 0, stream>>>(irA, Ht, wet, twg);
    k_stage2<<<dim3(NSIG * N1), 256, 0, stream>>>(bufA, bufA, Ht, twg);
    k_stage3<<<dim3(256), 1024, 0, stream>>>(bufA, out);
}

// Round 7
// 193.653 us; speedup vs baseline: 1.8276x; 1.8276x over previous
//
#include <hip/hip_runtime.h>
#include <hip/hip_cooperative_groups.h>
#include <math.h>

namespace cg = cooperative_groups;

constexpr int NFFT = 524288;   // 2^19 >= T + L - 1 = 485099
constexpr int N1   = 512;      // column FFT length (strided dim)
constexpr int N2   = 1024;     // row FFT length (contiguous dim)
constexpr int TT   = 441000;   // multiple of 4
constexpr int IRL  = 44100;    // multiple of 4
constexpr int NSIG = 16;       // 32 real batches packed as 16 complex signals
constexpr int C1   = 16;       // columns per tile in stage1/3
constexpr int TILE = N1 * C1;  // 8192 complex: one (all-k1 x 16-n2) tile

// bufA/irA layout is TILED: addr = (n2/16)*TILE + k1*16 + (n2%16).
// Ht stores H' = dry + wet*H (dry path folded into spectrum; FFT(delta)=1).

// -2*pi/NFFT
constexpr float ANG0   = -1.1984224905891939e-5f;
constexpr float NTWOPI = -6.2831853071795864769f;

__device__ inline float2 cmulf(float2 a, float2 b) {
    return make_float2(a.x * b.x - a.y * b.y, a.x * b.y + a.y * b.x);
}
__device__ inline float2 cadd(float2 a, float2 b) { return make_float2(a.x + b.x, a.y + b.y); }
__device__ inline float2 csub(float2 a, float2 b) { return make_float2(a.x - b.x, a.y - b.y); }

template<bool INV>
__device__ inline void bfly4(const float2* u, float2 w1, float2 w2, float2 w3, float2* o) {
    float2 t0 = cadd(u[0], u[2]);
    float2 t1 = csub(u[0], u[2]);
    float2 t2 = cadd(u[1], u[3]);
    float2 t3 = csub(u[1], u[3]);
    float2 r3 = INV ? make_float2(-t3.y, t3.x) : make_float2(t3.y, -t3.x);
    o[0] = cadd(t0, t2);
    o[1] = cmulf(cadd(t1, r3), w1);
    o[2] = cmulf(csub(t0, t2), w2);
    o[3] = cmulf(csub(t1, r3), w3);
}
template<bool INV>
__device__ inline void bfly4_nw(const float2* u, float2* o) {
    float2 t0 = cadd(u[0], u[2]);
    float2 t1 = csub(u[0], u[2]);
    float2 t2 = cadd(u[1], u[3]);
    float2 t3 = csub(u[1], u[3]);
    float2 r3 = INV ? make_float2(-t3.y, t3.x) : make_float2(t3.y, -t3.x);
    o[0] = cadd(t0, t2);
    o[1] = cadd(t1, r3);
    o[2] = csub(t0, t2);
    o[3] = csub(t1, r3);
}

// First 4 radix-4 passes (s=1,4,16,64) of the 512-FFT over 16 XOR-swizzled
// sequences; 1024 threads; twiddles from LDS table (W_512 in tw[0..511]).
template<bool INV>
__device__ void fft512_4p(float2* buf, const float2* tw, int tid) {
    const int f  = tid & 127;
    const int cb = tid >> 7;          // 0..7 (wave-uniform)
    int s = 1, logs = 0;
#pragma unroll
    for (int pass = 0; pass < 4; ++pass) {
        const int p = f >> logs;
        const int q = f & (s - 1);
        const int wb = q + 4 * s * p;
        const int e = p * s;
        float2 w1 = tw[e], w2 = tw[2 * e], w3 = tw[3 * e];
        if (INV) { w1.y = -w1.y; w2.y = -w2.y; w3.y = -w3.y; }
        float2 u[2][4];
#pragma unroll
        for (int k = 0; k < 2; ++k) {
            const int c = cb + 8 * k;
            float2* sb = buf + c * N1;
#pragma unroll
            for (int j = 0; j < 4; ++j) u[k][j] = sb[(f + 128 * j) ^ c];
        }
        __syncthreads();
#pragma unroll
        for (int k = 0; k < 2; ++k) {
            const int c = cb + 8 * k;
            float2* sb = buf + c * N1;
            float2 o[4];
            bfly4<INV>(u[k], w1, w2, w3, o);
            sb[wb ^ c]           = o[0];
            sb[(wb + s) ^ c]     = o[1];
            sb[(wb + 2 * s) ^ c] = o[2];
            sb[(wb + 3 * s) ^ c] = o[3];
        }
        __syncthreads();
        s <<= 2; logs += 2;
    }
}

// Radix-4 passes [FIRST, FIRST+COUNT) of the 1024-FFT; thread owns butterfly
// f = tid&255 of row r = tid>>8 (4 rows with 1024 threads).
template<bool INV, int FIRST, int COUNT>
__device__ void fft1024_mid(float2* buf, const float2* tw, int tid) {
    const int f = tid & 255;
    const int r = tid >> 8;
    float2* sb = buf + r * N2;
    int s = 1 << (2 * FIRST), logs = 2 * FIRST;
#pragma unroll
    for (int pass = 0; pass < COUNT; ++pass) {
        const int p = f >> logs;
        const int q = f & (s - 1);
        const int wb = q + 4 * s * p;
        const int e = p * s;
        float2 w1 = tw[e], w2 = tw[2 * e], w3 = tw[3 * e];
        if (INV) { w1.y = -w1.y; w2.y = -w2.y; w3.y = -w3.y; }
        float2 u[4];
#pragma unroll
        for (int j = 0; j < 4; ++j) u[j] = sb[f + 256 * j];
        __syncthreads();
        float2 o[4];
        bfly4<INV>(u, w1, w2, w3, o);
        sb[wb]         = o[0];
        sb[wb + s]     = o[1];
        sb[wb + 2 * s] = o[2];
        sb[wb + 3 * s] = o[3];
        __syncthreads();
        s <<= 2; logs += 2;
    }
}

// ================= fused cooperative kernel (all 4 stages) =================
// Each phase = the verified round-5 per-tile body inside a grid-stride loop.
// No registers carried across FFTs (round-6 scratch-spill lesson).
__global__ __launch_bounds__(1024, 4) void k_fused(
    const float* __restrict__ x, const float* __restrict__ ir,
    const float* __restrict__ wet_param, float* __restrict__ out,
    float2* __restrict__ Ht, float2* __restrict__ irA,
    float2* __restrict__ bufA)
{
    __shared__ __align__(16) float2 smem[C1 * N1];   // 64 KB
    __shared__ __align__(16) float2 tws[N2];         // 8 KB
    const int tid = threadIdx.x;
    const int nbl = gridDim.x;
    cg::grid_group grid = cg::this_grid();

    // ---------------- Phase 0: stage1 (fwd 512 column FFTs) ----------------
    if (tid < N1) {
        float sn, cs;
        __sincosf(NTWOPI * (float)tid * (1.0f / (float)N1), &sn, &cs);
        tws[tid] = make_float2(cs, sn);
    }
    __syncthreads();
    for (int t = blockIdx.x; t < 1088; t += nbl) {
        const int sig  = t >> 6;
        const int col0 = (t & 63) * C1;
        if (sig < NSIG) {
            const float* xa = x + (size_t)(2 * sig) * TT;
            const float* xb = xa + TT;
#pragma unroll
            for (int it = 0; it < 2; ++it) {
                const int qi = tid + 1024 * it;     // 2048 quads
                const int n1 = qi >> 2;
                const int c4 = (qi & 3) * 4;
                const int n  = n1 * N2 + col0 + c4; // n % 4 == 0
                float4 a4 = make_float4(0.f, 0.f, 0.f, 0.f);
                float4 b4 = a4;
                if (n < TT) {
                    a4 = *(const float4*)(xa + n);
                    b4 = *(const float4*)(xb + n);
                }
                smem[(c4 + 0) * N1 + (n1 ^ (c4 + 0))] = make_float2(a4.x, b4.x);
                smem[(c4 + 1) * N1 + (n1 ^ (c4 + 1))] = make_float2(a4.y, b4.y);
                smem[(c4 + 2) * N1 + (n1 ^ (c4 + 2))] = make_float2(a4.z, b4.z);
                smem[(c4 + 3) * N1 + (n1 ^ (c4 + 3))] = make_float2(a4.w, b4.w);
            }
        } else {
#pragma unroll
            for (int it = 0; it < 2; ++it) {
                const int qi = tid + 1024 * it;
                const int n1 = qi >> 2;
                const int c4 = (qi & 3) * 4;
                const int n  = n1 * N2 + col0 + c4;
                float4 a4 = make_float4(0.f, 0.f, 0.f, 0.f);
                if (n < IRL) a4 = *(const float4*)(ir + n);
                smem[(c4 + 0) * N1 + (n1 ^ (c4 + 0))] = make_float2(a4.x, 0.f);
                smem[(c4 + 1) * N1 + (n1 ^ (c4 + 1))] = make_float2(a4.y, 0.f);
                smem[(c4 + 2) * N1 + (n1 ^ (c4 + 2))] = make_float2(a4.z, 0.f);
                smem[(c4 + 3) * N1 + (n1 ^ (c4 + 3))] = make_float2(a4.w, 0.f);
            }
        }
        __syncthreads();

        fft512_4p<false>(smem, tws, tid);

        {   // final radix-2 + inter-stage twiddle + tiled store
            float2* dst  = (sig < NSIG) ? (bufA + (size_t)sig * NFFT) : irA;
            float2* dstt = dst + (size_t)(t & 63) * TILE;
            const int c  = tid & 15;
            const int fr = tid >> 4;          // 0..63
            const int n2 = col0 + c;
            float2 w0, s64, s256;
            float sn, cs;
            __sincosf(ANG0 * (float)(n2 * fr), &sn, &cs);   w0   = make_float2(cs, sn);
            __sincosf(ANG0 * (float)(n2 * 64), &sn, &cs);   s64  = make_float2(cs, sn);
            __sincosf(ANG0 * (float)(n2 * 256), &sn, &cs);  s256 = make_float2(cs, sn);
#pragma unroll
            for (int it = 0; it < 4; ++it) {
                const int fo = fr + 64 * it;  // 0..255
                float2 a  = smem[c * N1 + (fo ^ c)];
                float2 b2 = smem[c * N1 + ((fo + 256) ^ c)];
                float2 X0 = cadd(a, b2);
                float2 X1 = csub(a, b2);
                dstt[fo * C1 + c]         = cmulf(X0, w0);
                dstt[(fo + 256) * C1 + c] = cmulf(X1, cmulf(w0, s256));
                w0 = cmulf(w0, s64);
            }
        }
        __syncthreads();   // WAR before next tile's LDS writes
    }
    grid.sync();

    // ---------------- Phase 1: stage2_ir (H' = dry + wet*H) ----------------
    {
        float sn, cs;
        __sincosf(NTWOPI * (float)tid * (1.0f / (float)N2), &sn, &cs);
        tws[tid] = make_float2(cs, sn);   // W_1024, used by phases 1 & 2
    }
    __syncthreads();
    {
        const float wet = 1.0f / (1.0f + expf(-wet_param[0]));
        const float dry = 1.0f - wet;
        for (int g = blockIdx.x; g < N1 / 4; g += nbl) {
            const int r0 = g * 4;
#pragma unroll
            for (int it = 0; it < 2; ++it) {
                const int qi   = tid + 1024 * it;   // 2048 float4 = 4 rows
                const int r    = qi >> 9;
                const int np   = qi & 511;
                const int tile = np >> 3;
                const int q8   = np & 7;
                const int k1   = r0 + r;
                ((float4*)smem)[qi] =
                    ((const float4*)irA)[(size_t)tile * (TILE / 2) + k1 * 8 + q8];
            }
            __syncthreads();
            fft1024_mid<false, 0, 4>(smem, tws, tid);
            const int f = tid & 255;
            const int r = tid >> 8;
            float2 u[4], o[4];
#pragma unroll
            for (int j = 0; j < 4; ++j) u[j] = smem[r * N2 + f + 256 * j];
            bfly4_nw<false>(u, o);
#pragma unroll
            for (int j = 0; j < 4; ++j)
                Ht[(size_t)(r0 + r) * N2 + f + 256 * j] =
                    make_float2(dry + wet * o[j].x, wet * o[j].y);
            __syncthreads();
        }
    }
    grid.sync();

    // ---------------- Phase 2: stage2 (fwd*H'*inv, in-place) ---------------
    for (int g = blockIdx.x; g < NSIG * N1 / 4; g += nbl) {
        const int r0 = g * 4;
        const int sg = r0 >> 9;          // same signal for all 4 rows
#pragma unroll
        for (int it = 0; it < 2; ++it) {
            const int qi   = tid + 1024 * it;
            const int r    = qi >> 9;
            const int np   = qi & 511;
            const int tile = np >> 3;
            const int q8   = np & 7;
            const int k1r  = (r0 + r) & (N1 - 1);
            ((float4*)smem)[qi] =
                ((const float4*)bufA)[(size_t)sg * (NFFT / 2) +
                                      (size_t)tile * (TILE / 2) + k1r * 8 + q8];
        }
        const int f  = tid & 255;
        const int r  = tid >> 8;
        const int k1 = (r0 + r) & (N1 - 1);
        float2 h[4];
#pragma unroll
        for (int j = 0; j < 4; ++j) h[j] = Ht[(size_t)k1 * N2 + f + 256 * j];
        __syncthreads();

        fft1024_mid<false, 0, 4>(smem, tws, tid);

        {   // fwd p4 (unit tw) -> * H' -> inv p0, in regs
            float2 u[4];
#pragma unroll
            for (int j = 0; j < 4; ++j) u[j] = smem[r * N2 + f + 256 * j];
            __syncthreads();   // WAR guard
            float2 w1 = tws[f], w2 = tws[2 * f], w3 = tws[3 * f];
            w1.y = -w1.y; w2.y = -w2.y; w3.y = -w3.y;
            float2 o[4], v[4], o2[4];
            bfly4_nw<false>(u, o);
#pragma unroll
            for (int j = 0; j < 4; ++j) v[j] = cmulf(o[j], h[j]);
            bfly4<true>(v, w1, w2, w3, o2);
            float2* sb = smem + r * N2;
#pragma unroll
            for (int j = 0; j < 4; ++j) sb[4 * f + j] = o2[j];   // wb=4f, s=1
            __syncthreads();
        }

        fft1024_mid<true, 1, 3>(smem, tws, tid);   // inv passes s=4,16,64

        // inv final pass (s=256, unit tw) + conj twiddle recurrence + store
        float2 u[4], o[4];
#pragma unroll
        for (int j = 0; j < 4; ++j) u[j] = smem[r * N2 + f + 256 * j];
        bfly4_nw<true>(u, o);
        float2 w, st;
        {
            float sn, cs;
            __sincosf(-ANG0 * (float)(f * k1), &sn, &cs);   w  = make_float2(cs, sn);
            __sincosf(-ANG0 * (float)(256 * k1), &sn, &cs); st = make_float2(cs, sn);
        }
        float2* db = bufA + (size_t)sg * NFFT;
#pragma unroll
        for (int j = 0; j < 4; ++j) {
            const int n2 = f + 256 * j;
            db[(size_t)(n2 >> 4) * TILE + k1 * C1 + (n2 & 15)] = cmulf(o[j], w);
            w = cmulf(w, st);
        }
        __syncthreads();   // WAR before next group's LDS writes
    }
    grid.sync();

    // ---------------- Phase 3: stage3 (inv 512 column FFTs) ----------------
    if (tid < N1) {
        float sn, cs;
        __sincosf(NTWOPI * (float)tid * (1.0f / (float)N1), &sn, &cs);
        tws[tid] = make_float2(cs, sn);
    }
    __syncthreads();
    {
        const float wsc = 1.0f / (float)NFFT;
        for (int t = blockIdx.x; t < 1024; t += nbl) {
            const int sig  = t >> 6;
            const int col0 = (t & 63) * C1;
            const float2* st = bufA + (size_t)sig * NFFT + (size_t)(t & 63) * TILE;
            const int cp  = tid & 7;
            const int k1b = tid >> 3;
#pragma unroll
            for (int it = 0; it < 4; ++it) {
                const int k1 = k1b + 128 * it;
                float4 v = ((const float4*)st)[k1 * 8 + cp];   // contiguous tile
                const int ca = 2 * cp, cb2 = 2 * cp + 1;
                smem[ca * N1 + (k1 ^ ca)]   = make_float2(v.x, v.y);
                smem[cb2 * N1 + (k1 ^ cb2)] = make_float2(v.z, v.w);
            }
            __syncthreads();

            fft512_4p<true>(smem, tws, tid);

            float* oa = out + (size_t)(2 * sig) * TT;
            float* ob = oa + TT;
            const int c4 = (tid & 3) * 4;
            const int fo = tid >> 2;          // 0..255
            float2 y0[4], y1[4];
#pragma unroll
            for (int jj = 0; jj < 4; ++jj) {
                const int c = c4 + jj;
                float2 a  = smem[c * N1 + (fo ^ c)];
                float2 b2 = smem[c * N1 + ((fo + 256) ^ c)];
                y0[jj] = cadd(a, b2);
                y1[jj] = csub(a, b2);
            }
#pragma unroll
            for (int h = 0; h < 2; ++h) {
                const int row = fo + 256 * h;
                const int n   = row * N2 + col0 + c4;
                if (n < TT) {
                    const float2* yy = h ? y1 : y0;
                    float4 ra, rb2;
                    ra.x = wsc * yy[0].x;  ra.y = wsc * yy[1].x;
                    ra.z = wsc * yy[2].x;  ra.w = wsc * yy[3].x;
                    rb2.x = wsc * yy[0].y; rb2.y = wsc * yy[1].y;
                    rb2.z = wsc * yy[2].y; rb2.w = wsc * yy[3].y;
                    *(float4*)(oa + n) = ra;
                    *(float4*)(ob + n) = rb2;
                }
            }
            __syncthreads();
        }
    }
}

// ============ fallback path: verified round-5 separate kernels ============

__global__ __launch_bounds__(1024) void k_stage1(const float* __restrict__ x,
                                                 const float* __restrict__ ir,
                                                 float2* __restrict__ bufA,
                                                 float2* __restrict__ irA) {
    __shared__ float2 buf[C1 * N1];
    __shared__ float2 tw[N1];
    const int sig  = blockIdx.y;
    const int col0 = blockIdx.x * C1;
    const int tid  = threadIdx.x;

    if (tid < N1) {
        float sn, cs;
        __sincosf(NTWOPI * (float)tid * (1.0f / (float)N1), &sn, &cs);
        tw[tid] = make_float2(cs, sn);
    }

    if (sig < NSIG) {
        const float* xa = x + (size_t)(2 * sig) * TT;
        const float* xb = xa + TT;
#pragma unroll
        for (int it = 0; it < 2; ++it) {
            const int qi = tid + 1024 * it;
            const int n1 = qi >> 2;
            const int c4 = (qi & 3) * 4;
            const int n  = n1 * N2 + col0 + c4;
            float4 a4 = make_float4(0.f, 0.f, 0.f, 0.f);
            float4 b4 = a4;
            if (n < TT) {
                a4 = *(const float4*)(xa + n);
                b4 = *(const float4*)(xb + n);
            }
            buf[(c4 + 0) * N1 + (n1 ^ (c4 + 0))] = make_float2(a4.x, b4.x);
            buf[(c4 + 1) * N1 + (n1 ^ (c4 + 1))] = make_float2(a4.y, b4.y);
            buf[(c4 + 2) * N1 + (n1 ^ (c4 + 2))] = make_float2(a4.z, b4.z);
            buf[(c4 + 3) * N1 + (n1 ^ (c4 + 3))] = make_float2(a4.w, b4.w);
        }
    } else {
#pragma unroll
        for (int it = 0; it < 2; ++it) {
            const int qi = tid + 1024 * it;
            const int n1 = qi >> 2;
            const int c4 = (qi & 3) * 4;
            const int n  = n1 * N2 + col0 + c4;
            float4 a4 = make_float4(0.f, 0.f, 0.f, 0.f);
            if (n < IRL) a4 = *(const float4*)(ir + n);
            buf[(c4 + 0) * N1 + (n1 ^ (c4 + 0))] = make_float2(a4.x, 0.f);
            buf[(c4 + 1) * N1 + (n1 ^ (c4 + 1))] = make_float2(a4.y, 0.f);
            buf[(c4 + 2) * N1 + (n1 ^ (c4 + 2))] = make_float2(a4.z, 0.f);
            buf[(c4 + 3) * N1 + (n1 ^ (c4 + 3))] = make_float2(a4.w, 0.f);
        }
    }
    __syncthreads();

    fft512_4p<false>(buf, tw, tid);

    float2* dst  = (sig < NSIG) ? (bufA + (size_t)sig * NFFT) : irA;
    float2* dstt = dst + (size_t)blockIdx.x * TILE;
    const int c  = tid & 15;
    const int fr = tid >> 4;
    const int n2 = col0 + c;
    float2 w0, s64, s256;
    {
        float sn, cs;
        __sincosf(ANG0 * (float)(n2 * fr), &sn, &cs);   w0   = make_float2(cs, sn);
        __sincosf(ANG0 * (float)(n2 * 64), &sn, &cs);   s64  = make_float2(cs, sn);
        __sincosf(ANG0 * (float)(n2 * 256), &sn, &cs);  s256 = make_float2(cs, sn);
    }
#pragma unroll
    for (int it = 0; it < 4; ++it) {
        const int fo = fr + 64 * it;
        float2 a = buf[c * N1 + (fo ^ c)];
        float2 b = buf[c * N1 + ((fo + 256) ^ c)];
        float2 X0 = cadd(a, b);
        float2 X1 = csub(a, b);
        dstt[fo * C1 + c]         = cmulf(X0, w0);
        dstt[(fo + 256) * C1 + c] = cmulf(X1, cmulf(w0, s256));
        w0 = cmulf(w0, s64);
    }
}

__global__ __launch_bounds__(256) void k_stage2_ir(const float2* __restrict__ src,
                                                   float2* __restrict__ dst,
                                                   const float* __restrict__ wet_param) {
    __shared__ float2 buf[N2];
    __shared__ float2 tw[N2];
    const int k1  = blockIdx.x;
    const int tid = threadIdx.x;

#pragma unroll
    for (int it = 0; it < 4; ++it) {
        const int j = tid + 256 * it;
        float sn, cs;
        __sincosf(NTWOPI * (float)j * (1.0f / (float)N2), &sn, &cs);
        tw[j] = make_float2(cs, sn);
    }
#pragma unroll
    for (int it = 0; it < 2; ++it) {
        const int qi   = tid + 256 * it;
        const int tile = qi >> 3;
        const int q8   = qi & 7;
        ((float4*)buf)[qi] =
            ((const float4*)src)[(size_t)tile * (TILE / 2) + k1 * 8 + q8];
    }
    __syncthreads();

    fft1024_mid<false, 0, 4>(buf, tw, tid);

    const float wet = 1.0f / (1.0f + expf(-wet_param[0]));
    const float dry = 1.0f - wet;

    const int f = tid;
    float2 u[4], o[4];
#pragma unroll
    for (int j = 0; j < 4; ++j) u[j] = buf[f + 256 * j];
    bfly4_nw<false>(u, o);
#pragma unroll
    for (int j = 0; j < 4; ++j)
        dst[(size_t)k1 * N2 + f + 256 * j] =
            make_float2(dry + wet * o[j].x, wet * o[j].y);
}

__global__ __launch_bounds__(256) void k_stage2(const float2* __restrict__ src,
                                                float2* __restrict__ dst,
                                                const float2* __restrict__ Ht) {
    __shared__ float2 buf[N2];
    __shared__ float2 tw[N2];
    const int flat = blockIdx.x;
    const int sg   = flat >> 9;
    const int k1   = flat & (N1 - 1);
    const int tid  = threadIdx.x;

#pragma unroll
    for (int it = 0; it < 4; ++it) {
        const int j = tid + 256 * it;
        float sn, cs;
        __sincosf(NTWOPI * (float)j * (1.0f / (float)N2), &sn, &cs);
        tw[j] = make_float2(cs, sn);
    }
#pragma unroll
    for (int it = 0; it < 2; ++it) {
        const int qi   = tid + 256 * it;
        const int tile = qi >> 3;
        const int q8   = qi & 7;
        ((float4*)buf)[qi] =
            ((const float4*)src)[(size_t)sg * (NFFT / 2) +
                                 (size_t)tile * (TILE / 2) + k1 * 8 + q8];
    }
    const int f = tid;
    float2 h[4];
#pragma unroll
    for (int j = 0; j < 4; ++j) h[j] = Ht[(size_t)k1 * N2 + f + 256 * j];
    __syncthreads();

    fft1024_mid<false, 0, 4>(buf, tw, tid);

    {
        float2 u[4];
#pragma unroll
        for (int j = 0; j < 4; ++j) u[j] = buf[f + 256 * j];
        __syncthreads();
        float2 w1 = tw[f], w2 = tw[2 * f], w3 = tw[3 * f];
        w1.y = -w1.y; w2.y = -w2.y; w3.y = -w3.y;
        float2 o[4], v[4], o2[4];
        bfly4_nw<false>(u, o);
#pragma unroll
        for (int j = 0; j < 4; ++j) v[j] = cmulf(o[j], h[j]);
        bfly4<true>(v, w1, w2, w3, o2);
#pragma unroll
        for (int j = 0; j < 4; ++j) buf[4 * f + j] = o2[j];
        __syncthreads();
    }

    fft1024_mid<true, 1, 3>(buf, tw, tid);

    float2 u[4], o[4];
#pragma unroll
    for (int j = 0; j < 4; ++j) u[j] = buf[f + 256 * j];
    bfly4_nw<true>(u, o);
    float2 w, st;
    {
        float sn, cs;
        __sincosf(-ANG0 * (float)(f * k1), &sn, &cs);   w  = make_float2(cs, sn);
        __sincosf(-ANG0 * (float)(256 * k1), &sn, &cs); st = make_float2(cs, sn);
    }
    float2* db = dst + (size_t)sg * NFFT;
#pragma unroll
    for (int j = 0; j < 4; ++j) {
        const int n2 = f + 256 * j;
        db[(size_t)(n2 >> 4) * TILE + k1 * C1 + (n2 & 15)] = cmulf(o[j], w);
        w = cmulf(w, st);
    }
}

__global__ __launch_bounds__(1024) void k_stage3(const float2* __restrict__ bufB,
                                                 float* __restrict__ out) {
    __shared__ float2 buf[C1 * N1];
    __shared__ float2 tw[N1];
    const int sig  = blockIdx.y;
    const int col0 = blockIdx.x * C1;
    const int tid  = threadIdx.x;

    if (tid < N1) {
        float sn, cs;
        __sincosf(NTWOPI * (float)tid * (1.0f / (float)N1), &sn, &cs);
        tw[tid] = make_float2(cs, sn);
    }

    const float2* st = bufB + (size_t)sig * NFFT + (size_t)blockIdx.x * TILE;
    {
        const int cp  = tid & 7;
        const int k1b = tid >> 3;
#pragma unroll
        for (int it = 0; it < 4; ++it) {
            const int k1 = k1b + 128 * it;
            float4 v = ((const float4*)st)[k1 * 8 + cp];
            const int ca = 2 * cp, cb2 = 2 * cp + 1;
            buf[ca * N1 + (k1 ^ ca)]   = make_float2(v.x, v.y);
            buf[cb2 * N1 + (k1 ^ cb2)] = make_float2(v.z, v.w);
        }
    }
    __syncthreads();

    fft512_4p<true>(buf, tw, tid);

    const float ws = 1.0f / (float)NFFT;
    float* oa = out + (size_t)(2 * sig) * TT;
    float* ob = oa + TT;

    const int c4 = (tid & 3) * 4;
    const int fo = tid >> 2;
    float2 y0[4], y1[4];
#pragma unroll
    for (int jj = 0; jj < 4; ++jj) {
        const int c = c4 + jj;
        float2 a = buf[c * N1 + (fo ^ c)];
        float2 b = buf[c * N1 + ((fo + 256) ^ c)];
        y0[jj] = cadd(a, b);
        y1[jj] = csub(a, b);
    }
#pragma unroll
    for (int h = 0; h < 2; ++h) {
        const int row = fo + 256 * h;
        const int n   = row * N2 + col0 + c4;
        if (n < TT) {
            const float2* yy = h ? y1 : y0;
            float4 ra, rb2;
            ra.x = ws * yy[0].x;  ra.y = ws * yy[1].x;
            ra.z = ws * yy[2].x;  ra.w = ws * yy[3].x;
            rb2.x = ws * yy[0].y; rb2.y = ws * yy[1].y;
            rb2.z = ws * yy[2].y; rb2.w = ws * yy[3].y;
            *(float4*)(oa + n) = ra;
            *(float4*)(ob + n) = rb2;
        }
    }
}

// Correctness fallback if workspace is too small: direct time-domain conv.
__global__ __launch_bounds__(256) void k_direct(const float* __restrict__ x,
                                                const float* __restrict__ ir,
                                                const float* __restrict__ wet_param,
                                                float* __restrict__ out) {
    __shared__ float irs[1024];
    const int b = blockIdx.y;
    const int n = blockIdx.x * 256 + threadIdx.x;
    float acc = 0.0f;
    for (int k0 = 0; k0 < IRL; k0 += 1024) {
        __syncthreads();
        for (int j = threadIdx.x; j < 1024; j += 256) {
            const int k = k0 + j;
            irs[j] = (k < IRL) ? ir[k] : 0.0f;
        }
        __syncthreads();
        if (n < TT) {
            const int kend = min(1024, n - k0 + 1);
            for (int k = 0; k < kend; ++k)
                acc += irs[k] * x[(size_t)b * TT + (n - k0 - k)];
        }
    }
    if (n < TT) {
        const float wet = 1.0f / (1.0f + expf(-wet_param[0]));
        out[(size_t)b * TT + n] = (1.0f - wet) * x[(size_t)b * TT + n] + wet * acc;
    }
}

extern "C" void kernel_launch(void* const* d_in, const int* in_sizes, int n_in,
                              void* d_out, int out_size, void* d_ws, size_t ws_size,
                              hipStream_t stream) {
    (void)in_sizes; (void)n_in; (void)out_size;
    const float* x   = (const float*)d_in[0];
    const float* ir  = (const float*)d_in[1];
    const float* wet = (const float*)d_in[2];
    float* out = (float*)d_out;

    const size_t need = (size_t)(2 + NSIG) * (size_t)NFFT * sizeof(float2);
    if (ws_size < need) {
        dim3 g((TT + 255) / 256, 32);
        k_direct<<<g, 256, 0, stream>>>(x, ir, wet, out);
        return;
    }

    float2* Ht   = (float2*)d_ws;
    float2* irA  = Ht + NFFT;
    float2* bufA = irA + NFFT;

    // Primary path: single cooperative kernel (removes 3 inter-kernel gaps).
    static int coop_grid = -1;
    if (coop_grid < 0) {
        int mb = 0;
        if (hipOccupancyMaxActiveBlocksPerMultiprocessor(&mb, k_fused, 1024, 0)
                != hipSuccess) mb = 0;
        coop_grid = (mb >= 2) ? 512 : (mb >= 1 ? 256 : 0);
    }
    if (coop_grid > 0) {
        void* args[] = { (void*)&x, (void*)&ir, (void*)&wet, (void*)&out,
                         (void*)&Ht, (void*)&irA, (void*)&bufA };
        if (hipLaunchCooperativeKernel(k_fused, dim3(coop_grid), dim3(1024),
                                       args, 0, stream) == hipSuccess)
            return;
        coop_grid = 0;   // don't retry; fall through to 4-kernel path
    }

    // Fallback: verified round-5 four-kernel pipeline.
    k_stage1<<<dim3(N2 / C1, NSIG + 1), 1024, 0, stream>>>(x, ir, bufA, irA);
    k_stage2_ir<<<dim3(N1), 256, 0, stream>>>(irA, Ht, wet);
    k_stage2<<<dim3(NSIG * N1), 256, 0, stream>>>(bufA, bufA, Ht);
    k_stage3<<<dim3(N2 / C1, NSIG), 1024, 0, stream>>>(bufA, out);
}